// Round 1
// baseline (1603.974 us; speedup 1.0000x reference)
//
#include <hip/hip_runtime.h>
#include <math.h>

#define BATCH 2
#define CCH   512
#define NSP   4096
#define NHEAD 8
#define HDIM  64
#define NGRP  32
#define CPG   16
#define EPSV  1e-5f

// ---------------- GroupNorm stats: one block per (b,g) ----------------
__global__ __launch_bounds__(256) void gn_stats(const float* __restrict__ x,
                                                float* __restrict__ stats) {
    const int bg = blockIdx.x;  // 0..63 ; group channels are contiguous
    const float4* p = (const float4*)(x + (size_t)bg * (CPG * NSP));
    float s = 0.f, ss = 0.f;
    for (int i = threadIdx.x; i < CPG * NSP / 4; i += 256) {
        float4 v = p[i];
        s  += v.x + v.y + v.z + v.w;
        ss += v.x * v.x + v.y * v.y + v.z * v.z + v.w * v.w;
    }
    for (int o = 32; o > 0; o >>= 1) {
        s  += __shfl_down(s, o);
        ss += __shfl_down(ss, o);
    }
    __shared__ float shs[4], shss[4];
    const int wid = threadIdx.x >> 6, lane = threadIdx.x & 63;
    if (lane == 0) { shs[wid] = s; shss[wid] = ss; }
    __syncthreads();
    if (threadIdx.x == 0) {
        s  = shs[0] + shs[1] + shs[2] + shs[3];
        ss = shss[0] + shss[1] + shss[2] + shss[3];
        const float inv = 1.f / (float)(CPG * NSP);
        float mu  = s * inv;
        float var = ss * inv - mu * mu;
        stats[bg]      = mu;
        stats[64 + bg] = rsqrtf(var + EPSV);
    }
}

// ---------------- GroupNorm apply ----------------
__global__ __launch_bounds__(256) void gn_apply(const float* __restrict__ x,
                                                const float* __restrict__ stats,
                                                const float* __restrict__ nw,
                                                const float* __restrict__ nb,
                                                float* __restrict__ hn) {
    const size_t i = (size_t)blockIdx.x * 256 + threadIdx.x;  // float4 index
    const int c  = (int)((i >> 10) & 511);   // N/4 = 1024
    const int b  = (int)(i >> 19);           // C*N/4 = 524288
    const int bg = b * NGRP + (c >> 4);
    const float mu = stats[bg], rs = stats[64 + bg];
    const float sw = nw[c] * rs;
    const float sb = nb[c] - mu * sw;
    float4 v = ((const float4*)x)[i];
    float4 o;
    o.x = v.x * sw + sb;
    o.y = v.y * sw + sb;
    o.z = v.z * sw + sb;
    o.w = v.w * sw + sb;
    ((float4*)hn)[i] = o;
}

// ---------------- fp32 GEMM: out[b,m,n] = W[m,:]·Bm[b,:,n] + bias[m] (+resid) ----------------
// Tile 64x64, BK=16, 4x4 micro-tile. A staged transposed -> both LDS reads are b128.
__global__ __launch_bounds__(256) void gemm_nc(const float* __restrict__ W,
                                               const float* __restrict__ Bm,
                                               const float* __restrict__ bias,
                                               const float* __restrict__ resid,
                                               float* __restrict__ out,
                                               int M) {
    const int K = 512;
    __shared__ float As[16][68];   // [k][m] pad 68: b128-aligned rows, 2-way banks
    __shared__ float Bs[16][64];   // [k][n]
    const int b  = blockIdx.z;
    const int m0 = blockIdx.y * 64;
    const int n0 = blockIdx.x * 64;
    const int t  = threadIdx.x;
    const int tm = t >> 4, tn = t & 15;
    const float* Bb = Bm + (size_t)b * K * NSP;

    const int lm  = t >> 2;          // A-load: row m (0..63)
    const int lk4 = (t & 3) * 4;     // A-load: k offset
    const int lkb = t >> 4;          // B-load: row k (0..15)
    const int ln4 = (t & 15) * 4;    // B-load: n offset

    float acc[4][4] = {};
    for (int k0 = 0; k0 < K; k0 += 16) {
        float4 av = *(const float4*)&W[(size_t)(m0 + lm) * K + k0 + lk4];
        float4 bv = *(const float4*)&Bb[(size_t)(k0 + lkb) * NSP + n0 + ln4];
        __syncthreads();             // previous tile's reads complete
        As[lk4 + 0][lm] = av.x;
        As[lk4 + 1][lm] = av.y;
        As[lk4 + 2][lm] = av.z;
        As[lk4 + 3][lm] = av.w;
        *(float4*)&Bs[lkb][ln4] = bv;
        __syncthreads();
#pragma unroll
        for (int kk = 0; kk < 16; kk++) {
            float4 a4 = *(const float4*)&As[kk][tm * 4];
            float4 b4 = *(const float4*)&Bs[kk][tn * 4];
            acc[0][0] += a4.x * b4.x; acc[0][1] += a4.x * b4.y;
            acc[0][2] += a4.x * b4.z; acc[0][3] += a4.x * b4.w;
            acc[1][0] += a4.y * b4.x; acc[1][1] += a4.y * b4.y;
            acc[1][2] += a4.y * b4.z; acc[1][3] += a4.y * b4.w;
            acc[2][0] += a4.z * b4.x; acc[2][1] += a4.z * b4.y;
            acc[2][2] += a4.z * b4.z; acc[2][3] += a4.z * b4.w;
            acc[3][0] += a4.w * b4.x; acc[3][1] += a4.w * b4.y;
            acc[3][2] += a4.w * b4.z; acc[3][3] += a4.w * b4.w;
        }
    }
#pragma unroll
    for (int i = 0; i < 4; i++) {
        const int m = m0 + tm * 4 + i;
        const float bi = bias[m];
        const size_t base = ((size_t)b * M + m) * NSP + n0 + tn * 4;
        float4 r;
        r.x = acc[i][0] + bi; r.y = acc[i][1] + bi;
        r.z = acc[i][2] + bi; r.w = acc[i][3] + bi;
        if (resid) {
            float4 rv = *(const float4*)&resid[base];
            r.x += rv.x; r.y += rv.y; r.z += rv.z; r.w += rv.w;
        }
        *(float4*)&out[base] = r;
    }
}

// ---------------- flash attention, fp32 ----------------
// Block = (query-tile 64, head, batch). Q resident in LDS; K and V share KVs.
__global__ __launch_bounds__(256) void attn_flash(const float* __restrict__ qkv,
                                                  float* __restrict__ attno) {
    __shared__ float Qs[64][68];   // [d][qi]
    __shared__ float KVs[64][68];  // [d][mi] (K, then V)
    __shared__ float Ss[64][68];   // [qi][mi]
    __shared__ float mrow[64], lrow[64], arow[64];

    const int qt = blockIdx.x;     // 0..63
    const int h  = blockIdx.y;     // 0..7
    const int b  = blockIdx.z;     // 0..1
    const int t  = threadIdx.x;
    const int tq = t & 15, td = t >> 4;
    const int ld = t >> 2;         // load row (d), 0..63
    const int lc = (t & 3);        // load col group

    const size_t qbase = ((size_t)b * 3 * CCH + h * HDIM) * NSP;
    const size_t kbase = qbase + (size_t)CCH * NSP;
    const size_t vbase = qbase + (size_t)2 * CCH * NSP;

    {
        const float* src = qkv + qbase + (size_t)ld * NSP + qt * 64;
#pragma unroll
        for (int r = 0; r < 4; r++) {
            const int qi = (lc + r * 4) * 4;
            *(float4*)&Qs[ld][qi] = *(const float4*)&src[qi];
        }
    }
    if (t < 64) { mrow[t] = -1e30f; lrow[t] = 0.f; }

    float o[4][4] = {};  // o[i][j]: query tq*4+i, dim td*4+j

    for (int mt = 0; mt < 64; mt++) {
        __syncthreads();  // prev PV done with KVs/Ss
        {
            const float* src = qkv + kbase + (size_t)ld * NSP + mt * 64;
#pragma unroll
            for (int r = 0; r < 4; r++) {
                const int mi = (lc + r * 4) * 4;
                *(float4*)&KVs[ld][mi] = *(const float4*)&src[mi];
            }
        }
        __syncthreads();  // K ready
        {
            float s[4][4] = {};
#pragma unroll 8
            for (int d = 0; d < 64; d++) {
                float4 aq = *(const float4*)&Qs[d][tq * 4];
                float4 bk = *(const float4*)&KVs[d][td * 4];
                s[0][0] += aq.x * bk.x; s[0][1] += aq.x * bk.y;
                s[0][2] += aq.x * bk.z; s[0][3] += aq.x * bk.w;
                s[1][0] += aq.y * bk.x; s[1][1] += aq.y * bk.y;
                s[1][2] += aq.y * bk.z; s[1][3] += aq.y * bk.w;
                s[2][0] += aq.z * bk.x; s[2][1] += aq.z * bk.y;
                s[2][2] += aq.z * bk.z; s[2][3] += aq.z * bk.w;
                s[3][0] += aq.w * bk.x; s[3][1] += aq.w * bk.y;
                s[3][2] += aq.w * bk.z; s[3][3] += aq.w * bk.w;
            }
#pragma unroll
            for (int i = 0; i < 4; i++)
#pragma unroll
                for (int j = 0; j < 4; j++)
                    Ss[tq * 4 + i][td * 4 + j] = s[i][j] * 0.125f;
        }
        __syncthreads();  // Ss ready, K consumed
        {
            // all threads: load V into KVs; threads <64: row softmax on Ss
            const float* src = qkv + vbase + (size_t)ld * NSP + mt * 64;
#pragma unroll
            for (int r = 0; r < 4; r++) {
                const int mi = (lc + r * 4) * 4;
                *(float4*)&KVs[ld][mi] = *(const float4*)&src[mi];
            }
            if (t < 64) {
                const float om = mrow[t];
                float mx = om;
                const float4* srow = (const float4*)&Ss[t][0];
#pragma unroll
                for (int c4 = 0; c4 < 16; c4++) {
                    float4 v = srow[c4];
                    mx = fmaxf(mx, fmaxf(fmaxf(v.x, v.y), fmaxf(v.z, v.w)));
                }
                const float al = __expf(om - mx);
                float sum = 0.f;
                float4* wrow = (float4*)&Ss[t][0];
#pragma unroll
                for (int c4 = 0; c4 < 16; c4++) {
                    float4 v = wrow[c4];
                    v.x = __expf(v.x - mx); v.y = __expf(v.y - mx);
                    v.z = __expf(v.z - mx); v.w = __expf(v.w - mx);
                    sum += v.x + v.y + v.z + v.w;
                    wrow[c4] = v;
                }
                mrow[t] = mx;
                lrow[t] = lrow[t] * al + sum;
                arow[t] = al;
            }
        }
        __syncthreads();  // V + P + alpha ready
        {
#pragma unroll
            for (int i = 0; i < 4; i++) {
                const float al = arow[tq * 4 + i];
                o[i][0] *= al; o[i][1] *= al; o[i][2] *= al; o[i][3] *= al;
            }
#pragma unroll 4
            for (int m4 = 0; m4 < 16; m4++) {
                float4 p[4], v[4];
#pragma unroll
                for (int i = 0; i < 4; i++) p[i] = *(const float4*)&Ss[tq * 4 + i][m4 * 4];
#pragma unroll
                for (int j = 0; j < 4; j++) v[j] = *(const float4*)&KVs[td * 4 + j][m4 * 4];
#pragma unroll
                for (int i = 0; i < 4; i++)
#pragma unroll
                    for (int j = 0; j < 4; j++)
                        o[i][j] += p[i].x * v[j].x + p[i].y * v[j].y +
                                   p[i].z * v[j].z + p[i].w * v[j].w;
            }
        }
    }

    float inv[4];
#pragma unroll
    for (int i = 0; i < 4; i++) inv[i] = 1.f / lrow[tq * 4 + i];
#pragma unroll
    for (int j = 0; j < 4; j++) {
        const int d = td * 4 + j;
        const size_t base = ((size_t)b * CCH + h * HDIM + d) * NSP + qt * 64;
#pragma unroll
        for (int i = 0; i < 4; i++)
            attno[base + tq * 4 + i] = o[i][j] * inv[i];
    }
}

extern "C" void kernel_launch(void* const* d_in, const int* in_sizes, int n_in,
                              void* d_out, int out_size, void* d_ws, size_t ws_size,
                              hipStream_t stream) {
    const float* x    = (const float*)d_in[0];
    const float* nw   = (const float*)d_in[1];
    const float* nb   = (const float*)d_in[2];
    const float* qkvw = (const float*)d_in[3];
    const float* qkvb = (const float*)d_in[4];
    const float* pw   = (const float*)d_in[5];
    const float* pb   = (const float*)d_in[6];
    float* out = (float*)d_out;
    float* ws  = (float*)d_ws;

    float* stats = ws;                                  // 128 floats
    float* hn    = ws + 128;                            // B*C*N
    float* qkv   = hn + (size_t)BATCH * CCH * NSP;      // B*3C*N
    float* att   = qkv + (size_t)BATCH * 3 * CCH * NSP; // B*C*N

    hipLaunchKernelGGL(gn_stats, dim3(BATCH * NGRP), dim3(256), 0, stream, x, stats);
    hipLaunchKernelGGL(gn_apply, dim3(4096), dim3(256), 0, stream, x, stats, nw, nb, hn);
    hipLaunchKernelGGL(gemm_nc, dim3(NSP / 64, 3 * CCH / 64, BATCH), dim3(256), 0, stream,
                       qkvw, hn, qkvb, (const float*)nullptr, qkv, 3 * CCH);
    hipLaunchKernelGGL(attn_flash, dim3(NSP / 64, NHEAD, BATCH), dim3(256), 0, stream,
                       qkv, att);
    hipLaunchKernelGGL(gemm_nc, dim3(NSP / 64, CCH / 64, BATCH), dim3(256), 0, stream,
                       pw, att, pb, x, out, CCH);
}

// Round 2
// 627.139 us; speedup vs baseline: 2.5576x; 2.5576x over previous
//
#include <hip/hip_runtime.h>
#include <hip/hip_bf16.h>
#include <math.h>

#define BATCH 2
#define CCH   512
#define NSP   4096
#define NHEAD 8
#define HDIM  64
#define NGRP  32
#define CPG   16
#define EPSV  1e-5f

typedef __attribute__((ext_vector_type(8))) short short8;
typedef __attribute__((ext_vector_type(4))) short short4v;
typedef __attribute__((ext_vector_type(4))) float f32x4;

// ---------------- GroupNorm stats: one block per (b,g) ----------------
__global__ __launch_bounds__(256) void gn_stats(const float* __restrict__ x,
                                                float* __restrict__ stats) {
    const int bg = blockIdx.x;
    const float4* p = (const float4*)(x + (size_t)bg * (CPG * NSP));
    float s = 0.f, ss = 0.f;
    for (int i = threadIdx.x; i < CPG * NSP / 4; i += 256) {
        float4 v = p[i];
        s  += v.x + v.y + v.z + v.w;
        ss += v.x * v.x + v.y * v.y + v.z * v.z + v.w * v.w;
    }
    for (int o = 32; o > 0; o >>= 1) {
        s  += __shfl_down(s, o);
        ss += __shfl_down(ss, o);
    }
    __shared__ float shs[4], shss[4];
    const int wid = threadIdx.x >> 6, lane = threadIdx.x & 63;
    if (lane == 0) { shs[wid] = s; shss[wid] = ss; }
    __syncthreads();
    if (threadIdx.x == 0) {
        s  = shs[0] + shs[1] + shs[2] + shs[3];
        ss = shss[0] + shss[1] + shss[2] + shss[3];
        const float inv = 1.f / (float)(CPG * NSP);
        float mu  = s * inv;
        float var = ss * inv - mu * mu;
        stats[bg]      = mu;
        stats[64 + bg] = rsqrtf(var + EPSV);
    }
}

// ---------------- GroupNorm apply ----------------
__global__ __launch_bounds__(256) void gn_apply(const float* __restrict__ x,
                                                const float* __restrict__ stats,
                                                const float* __restrict__ nw,
                                                const float* __restrict__ nb,
                                                float* __restrict__ hn) {
    const size_t i = (size_t)blockIdx.x * 256 + threadIdx.x;
    const int c  = (int)((i >> 10) & 511);
    const int b  = (int)(i >> 19);
    const int bg = b * NGRP + (c >> 4);
    const float mu = stats[bg], rs = stats[64 + bg];
    const float sw = nw[c] * rs;
    const float sb = nb[c] - mu * sw;
    float4 v = ((const float4*)x)[i];
    float4 o;
    o.x = v.x * sw + sb;
    o.y = v.y * sw + sb;
    o.z = v.z * sw + sb;
    o.w = v.w * sw + sb;
    ((float4*)hn)[i] = o;
}

// ---------------- fp32 GEMM (QKV + proj) ----------------
__global__ __launch_bounds__(256) void gemm_nc(const float* __restrict__ W,
                                               const float* __restrict__ Bm,
                                               const float* __restrict__ bias,
                                               const float* __restrict__ resid,
                                               float* __restrict__ out,
                                               int M) {
    const int K = 512;
    __shared__ float As[16][68];
    __shared__ float Bs[16][64];
    const int b  = blockIdx.z;
    const int m0 = blockIdx.y * 64;
    const int n0 = blockIdx.x * 64;
    const int t  = threadIdx.x;
    const int tm = t >> 4, tn = t & 15;
    const float* Bb = Bm + (size_t)b * K * NSP;

    const int lm  = t >> 2;
    const int lk4 = (t & 3) * 4;
    const int lkb = t >> 4;
    const int ln4 = (t & 15) * 4;

    float acc[4][4] = {};
    for (int k0 = 0; k0 < K; k0 += 16) {
        float4 av = *(const float4*)&W[(size_t)(m0 + lm) * K + k0 + lk4];
        float4 bv = *(const float4*)&Bb[(size_t)(k0 + lkb) * NSP + n0 + ln4];
        __syncthreads();
        As[lk4 + 0][lm] = av.x;
        As[lk4 + 1][lm] = av.y;
        As[lk4 + 2][lm] = av.z;
        As[lk4 + 3][lm] = av.w;
        *(float4*)&Bs[lkb][ln4] = bv;
        __syncthreads();
#pragma unroll
        for (int kk = 0; kk < 16; kk++) {
            float4 a4 = *(const float4*)&As[kk][tm * 4];
            float4 b4 = *(const float4*)&Bs[kk][tn * 4];
            acc[0][0] += a4.x * b4.x; acc[0][1] += a4.x * b4.y;
            acc[0][2] += a4.x * b4.z; acc[0][3] += a4.x * b4.w;
            acc[1][0] += a4.y * b4.x; acc[1][1] += a4.y * b4.y;
            acc[1][2] += a4.y * b4.z; acc[1][3] += a4.y * b4.w;
            acc[2][0] += a4.z * b4.x; acc[2][1] += a4.z * b4.y;
            acc[2][2] += a4.z * b4.z; acc[2][3] += a4.z * b4.w;
            acc[3][0] += a4.w * b4.x; acc[3][1] += a4.w * b4.y;
            acc[3][2] += a4.w * b4.z; acc[3][3] += a4.w * b4.w;
        }
    }
#pragma unroll
    for (int i = 0; i < 4; i++) {
        const int m = m0 + tm * 4 + i;
        const float bi = bias[m];
        const size_t base = ((size_t)b * M + m) * NSP + n0 + tn * 4;
        float4 r;
        r.x = acc[i][0] + bi; r.y = acc[i][1] + bi;
        r.z = acc[i][2] + bi; r.w = acc[i][3] + bi;
        if (resid) {
            float4 rv = *(const float4*)&resid[base];
            r.x += rv.x; r.y += rv.y; r.z += rv.z; r.w += rv.w;
        }
        *(float4*)&out[base] = r;
    }
}

// ---------------- prep: Q/K transpose+cast to [bh][n][d] bf16 ----------------
__global__ __launch_bounds__(256) void prep_qk(const float* __restrict__ qkv,
                                               __hip_bfloat16* __restrict__ qt,
                                               __hip_bfloat16* __restrict__ kt) {
    const int t  = threadIdx.x;
    const int bh = blockIdx.y;
    const int b  = bh >> 3, h = bh & 7;
    const float* src = qkv + ((size_t)b * 1536 + blockIdx.z * 512 + h * 64) * NSP;
    __hip_bfloat16* dst = (blockIdx.z ? kt : qt) + (size_t)bh * NSP * HDIM;
    const int n  = blockIdx.x * 64 + (t >> 2);
    const int dc = (t & 3) * 16;
    alignas(16) __hip_bfloat16 buf[16];
#pragma unroll
    for (int i = 0; i < 16; i++)
        buf[i] = __float2bfloat16(src[(size_t)(dc + i) * NSP + n]);
    *(short8*)(dst + (size_t)n * HDIM + dc)     = *(short8*)&buf[0];
    *(short8*)(dst + (size_t)n * HDIM + dc + 8) = *(short8*)&buf[8];
}

// ---------------- prep: V cast to [bh][d][n] bf16 ----------------
__global__ __launch_bounds__(256) void prep_v(const float* __restrict__ qkv,
                                              __hip_bfloat16* __restrict__ vt) {
    const size_t i = (size_t)blockIdx.x * 256 + threadIdx.x;  // float4 index
    const int n4 = (int)(i & 1023);
    const int c  = (int)((i >> 10) & 511);
    const int b  = (int)(i >> 19);
    float4 v = *(const float4*)(qkv + ((size_t)(b * 1536 + 1024 + c)) * NSP + n4 * 4);
    alignas(8) __hip_bfloat16 o[4];
    o[0] = __float2bfloat16(v.x); o[1] = __float2bfloat16(v.y);
    o[2] = __float2bfloat16(v.z); o[3] = __float2bfloat16(v.w);
    *(short4v*)(vt + ((size_t)(b * 512 + c)) * NSP + n4 * 4) = *(short4v*)&o[0];
}

// ---------------- MFMA flash attention ----------------
// Block = 4 waves; wave handles 32 queries (2 x 16). All Q/K/V fragments come
// straight from global (16B/lane); only P round-trips through LDS.
__global__ __launch_bounds__(256) void attn_mfma(const __hip_bfloat16* __restrict__ qt,
                                                 const __hip_bfloat16* __restrict__ kt,
                                                 const __hip_bfloat16* __restrict__ vt,
                                                 float* __restrict__ att) {
    __shared__ __hip_bfloat16 Pl[4][2][16][80];  // row stride 160B: 16B-aligned, uniform banks
    const int t    = threadIdx.x;
    const int wave = t >> 6, lane = t & 63;
    const int quad = lane >> 4, l15 = lane & 15;
    const int bh   = blockIdx.z * NHEAD + blockIdx.y;
    const int qb   = blockIdx.x * 128 + wave * 32;

    const __hip_bfloat16* Qb = qt + (size_t)bh * NSP * HDIM;
    const __hip_bfloat16* Kb = kt + (size_t)bh * NSP * HDIM;
    const __hip_bfloat16* Vb = vt + (size_t)bh * HDIM * NSP;

    short8 qf[2][2];
#pragma unroll
    for (int qs = 0; qs < 2; qs++)
#pragma unroll
        for (int c = 0; c < 2; c++)
            qf[qs][c] = *(const short8*)(Qb + (size_t)(qb + qs * 16 + l15) * HDIM + c * 32 + quad * 8);

    f32x4 o[2][4];
    float mrow[2][4], lrow[2][4];
#pragma unroll
    for (int qs = 0; qs < 2; qs++)
#pragma unroll
        for (int d = 0; d < 4; d++) {
            o[qs][d] = (f32x4){0.f, 0.f, 0.f, 0.f};
            mrow[qs][d] = -1e30f;
            lrow[qs][d] = 0.f;
        }

    for (int mt = 0; mt < 64; mt++) {
        const int mb = mt * 64;
        // ---- QK^T: S[32q][64m] ----
        short8 kf[4][2];
#pragma unroll
        for (int ms = 0; ms < 4; ms++)
#pragma unroll
            for (int c = 0; c < 2; c++)
                kf[ms][c] = *(const short8*)(Kb + (size_t)(mb + ms * 16 + l15) * HDIM + c * 32 + quad * 8);

        f32x4 s[2][4];
#pragma unroll
        for (int qs = 0; qs < 2; qs++)
#pragma unroll
            for (int ms = 0; ms < 4; ms++) {
                f32x4 acc = (f32x4){0.f, 0.f, 0.f, 0.f};
                acc = __builtin_amdgcn_mfma_f32_16x16x32_bf16(qf[qs][0], kf[ms][0], acc, 0, 0, 0);
                acc = __builtin_amdgcn_mfma_f32_16x16x32_bf16(qf[qs][1], kf[ms][1], acc, 0, 0, 0);
                s[qs][ms] = acc * 0.125f;
            }

        __syncthreads();  // WAR guard on Pl vs previous iteration

        // ---- online softmax (rows = quad*4+r) ----
        float alpha[2][4];
#pragma unroll
        for (int qs = 0; qs < 2; qs++) {
#pragma unroll
            for (int r = 0; r < 4; r++) {
                float mx = fmaxf(fmaxf(s[qs][0][r], s[qs][1][r]),
                                 fmaxf(s[qs][2][r], s[qs][3][r]));
#pragma unroll
                for (int off = 1; off < 16; off <<= 1)
                    mx = fmaxf(mx, __shfl_xor(mx, off, 64));
                const float nm = fmaxf(mrow[qs][r], mx);
                alpha[qs][r] = __expf(mrow[qs][r] - nm);
                mrow[qs][r] = nm;
                float rs = 0.f;
#pragma unroll
                for (int ms = 0; ms < 4; ms++) {
                    float p = __expf(s[qs][ms][r] - nm);
                    s[qs][ms][r] = p;
                    rs += p;
                }
#pragma unroll
                for (int off = 1; off < 16; off <<= 1)
                    rs += __shfl_xor(rs, off, 64);
                lrow[qs][r] = lrow[qs][r] * alpha[qs][r] + rs;
            }
            // write P tile (C-layout -> LDS)
#pragma unroll
            for (int ms = 0; ms < 4; ms++)
#pragma unroll
                for (int r = 0; r < 4; r++)
                    Pl[wave][qs][quad * 4 + r][ms * 16 + l15] = __float2bfloat16(s[qs][ms][r]);
        }
        __syncthreads();  // P visible

        // ---- PV: O[32q][64d] += P * V^T ----
        short8 pf[2][2];
#pragma unroll
        for (int qs = 0; qs < 2; qs++)
#pragma unroll
            for (int c = 0; c < 2; c++)
                pf[qs][c] = *(const short8*)&Pl[wave][qs][l15][c * 32 + quad * 8];

        short8 vf[4][2];
#pragma unroll
        for (int ds = 0; ds < 4; ds++)
#pragma unroll
            for (int c = 0; c < 2; c++)
                vf[ds][c] = *(const short8*)(Vb + (size_t)(ds * 16 + l15) * NSP + mb + c * 32 + quad * 8);

#pragma unroll
        for (int qs = 0; qs < 2; qs++)
#pragma unroll
            for (int ds = 0; ds < 4; ds++) {
                f32x4 acc = o[qs][ds];
#pragma unroll
                for (int r = 0; r < 4; r++) acc[r] *= alpha[qs][r];
                acc = __builtin_amdgcn_mfma_f32_16x16x32_bf16(pf[qs][0], vf[ds][0], acc, 0, 0, 0);
                acc = __builtin_amdgcn_mfma_f32_16x16x32_bf16(pf[qs][1], vf[ds][1], acc, 0, 0, 0);
                o[qs][ds] = acc;
            }
    }

    // ---- epilogue: att[bh*64 + d][q] = O[q][d] / l ----
#pragma unroll
    for (int qs = 0; qs < 2; qs++) {
        float invl[4];
#pragma unroll
        for (int r = 0; r < 4; r++) invl[r] = 1.f / lrow[qs][r];
#pragma unroll
        for (int ds = 0; ds < 4; ds++) {
            const int d = ds * 16 + l15;
#pragma unroll
            for (int r = 0; r < 4; r++) {
                const int q = qb + qs * 16 + quad * 4 + r;
                att[((size_t)bh * 64 + d) * NSP + q] = o[qs][ds][r] * invl[r];
            }
        }
    }
}

extern "C" void kernel_launch(void* const* d_in, const int* in_sizes, int n_in,
                              void* d_out, int out_size, void* d_ws, size_t ws_size,
                              hipStream_t stream) {
    const float* x    = (const float*)d_in[0];
    const float* nw   = (const float*)d_in[1];
    const float* nb   = (const float*)d_in[2];
    const float* qkvw = (const float*)d_in[3];
    const float* qkvb = (const float*)d_in[4];
    const float* pw   = (const float*)d_in[5];
    const float* pb   = (const float*)d_in[6];
    float* out = (float*)d_out;
    char* ws   = (char*)d_ws;

    float* stats = (float*)ws;                                   // 512 B
    float* hn    = (float*)(ws + 512);                           // 16 MB (reused as att)
    float* qkv   = (float*)(ws + 512 + (size_t)16 * 1024 * 1024);// 48 MB
    char*  bfs   = ws + 512 + (size_t)64 * 1024 * 1024;
    __hip_bfloat16* qt = (__hip_bfloat16*)bfs;                            // 8 MB
    __hip_bfloat16* kt = (__hip_bfloat16*)(bfs + (size_t)8 * 1024 * 1024);
    __hip_bfloat16* vt = (__hip_bfloat16*)(bfs + (size_t)16 * 1024 * 1024);
    float* att = hn;  // hn dead after QKV GEMM

    hipLaunchKernelGGL(gn_stats, dim3(BATCH * NGRP), dim3(256), 0, stream, x, stats);
    hipLaunchKernelGGL(gn_apply, dim3(4096), dim3(256), 0, stream, x, stats, nw, nb, hn);
    hipLaunchKernelGGL(gemm_nc, dim3(NSP / 64, 3 * CCH / 64, BATCH), dim3(256), 0, stream,
                       qkvw, hn, qkvb, (const float*)nullptr, qkv, 3 * CCH);
    hipLaunchKernelGGL(prep_qk, dim3(NSP / 64, 16, 2), dim3(256), 0, stream, qkv, qt, kt);
    hipLaunchKernelGGL(prep_v, dim3(4096), dim3(256), 0, stream, qkv, vt);
    hipLaunchKernelGGL(attn_mfma, dim3(NSP / 128, NHEAD, BATCH), dim3(256), 0, stream,
                       qt, kt, vt, att);
    hipLaunchKernelGGL(gemm_nc, dim3(NSP / 64, CCH / 64, BATCH), dim3(256), 0, stream,
                       pw, att, pb, x, out, CCH);
}

// Round 3
// 422.002 us; speedup vs baseline: 3.8009x; 1.4861x over previous
//
#include <hip/hip_runtime.h>
#include <hip/hip_bf16.h>
#include <math.h>

#define BATCH 2
#define CCH   512
#define NSP   4096
#define NHEAD 8
#define HDIM  64
#define NGRP  32
#define CPG   16
#define EPSV  1e-5f
#define SMSCALE 0.1803368801111204f   // 0.125 * log2(e): folded into Q at QKV epilogue

typedef __attribute__((ext_vector_type(8))) short short8;
typedef __attribute__((ext_vector_type(4))) short short4v;
typedef __attribute__((ext_vector_type(4))) float f32x4;
typedef __hip_bfloat16 bf16;

static __device__ __forceinline__ bf16 tobf(float x) { return __float2bfloat16(x); }

// ---------------- cast weights to bf16 (once per launch) ----------------
__global__ __launch_bounds__(256) void wcast(const float* __restrict__ qkvw,
                                             const float* __restrict__ pw,
                                             bf16* __restrict__ wq, bf16* __restrict__ wp) {
    const int i = blockIdx.x * 256 + threadIdx.x;   // float4 index
    const int NQ = 1536 * 512 / 4;
    float4 v; bf16* dst; int di;
    if (i < NQ) { v = ((const float4*)qkvw)[i]; dst = wq; di = i; }
    else        { v = ((const float4*)pw)[i - NQ]; dst = wp; di = i - NQ; }
    alignas(8) bf16 o[4] = {tobf(v.x), tobf(v.y), tobf(v.z), tobf(v.w)};
    *(short4v*)(dst + (size_t)di * 4) = *(short4v*)o;
}

// ---------------- GroupNorm stats: one block per (b,g) ----------------
__global__ __launch_bounds__(256) void gn_stats(const float* __restrict__ x,
                                                float* __restrict__ stats) {
    const int bg = blockIdx.x;
    const float4* p = (const float4*)(x + (size_t)bg * (CPG * NSP));
    float s = 0.f, ss = 0.f;
    for (int i = threadIdx.x; i < CPG * NSP / 4; i += 256) {
        float4 v = p[i];
        s  += v.x + v.y + v.z + v.w;
        ss += v.x * v.x + v.y * v.y + v.z * v.z + v.w * v.w;
    }
    for (int o = 32; o > 0; o >>= 1) {
        s  += __shfl_down(s, o);
        ss += __shfl_down(ss, o);
    }
    __shared__ float shs[4], shss[4];
    const int wid = threadIdx.x >> 6, lane = threadIdx.x & 63;
    if (lane == 0) { shs[wid] = s; shss[wid] = ss; }
    __syncthreads();
    if (threadIdx.x == 0) {
        s  = shs[0] + shs[1] + shs[2] + shs[3];
        ss = shss[0] + shss[1] + shss[2] + shss[3];
        const float inv = 1.f / (float)(CPG * NSP);
        float mu  = s * inv;
        float var = ss * inv - mu * mu;
        stats[bg]      = mu;
        stats[64 + bg] = rsqrtf(var + EPSV);
    }
}

// ---------------- GroupNorm apply + transpose + cast: hnt[b][n][c] bf16 ----------------
__global__ __launch_bounds__(256) void gn_apply_t(const float* __restrict__ x,
                                                  const float* __restrict__ stats,
                                                  const float* __restrict__ nw,
                                                  const float* __restrict__ nb,
                                                  bf16* __restrict__ hnt) {
    __shared__ float Ls[64][68];
    const int b  = blockIdx.z;
    const int c0 = blockIdx.y * 64;
    const int n0 = blockIdx.x * 64;
    const int t  = threadIdx.x;
    const int cl = t >> 4, n4 = (t & 15) * 4;
#pragma unroll
    for (int ph = 0; ph < 4; ph++) {
        const int c  = c0 + ph * 16 + cl;
        const int bg = b * NGRP + (c >> 4);
        const float mu = stats[bg], rs = stats[64 + bg];
        const float sw = nw[c] * rs;
        const float sb = nb[c] - mu * sw;
        float4 v = *(const float4*)&x[((size_t)b * CCH + c) * NSP + n0 + n4];
        float4 o;
        o.x = v.x * sw + sb; o.y = v.y * sw + sb;
        o.z = v.z * sw + sb; o.w = v.w * sw + sb;
        *(float4*)&Ls[ph * 16 + cl][n4] = o;
    }
    __syncthreads();
#pragma unroll
    for (int ph = 0; ph < 2; ph++) {
        const int task = ph * 256 + t;
        const int nl = task & 63, cc = (task >> 6) * 8;
        alignas(16) bf16 buf[8];
#pragma unroll
        for (int j = 0; j < 8; j++) buf[j] = tobf(Ls[cc + j][nl]);
        *(short8*)&hnt[((size_t)b * NSP + n0 + nl) * CCH + c0 + cc] = *(short8*)buf;
    }
}

// ---------------- bf16 MFMA GEMM: QKV. C[m][n] = W[m,:]·hnt[n,:]^T ----------------
// Block 128m x 128n, wave 64x64. Writes q/k as [bh][n][d] bf16 (q pre-scaled), v as [bh][d][n].
__global__ __launch_bounds__(256) void gemm_qkv(const bf16* __restrict__ Wb,
                                                const bf16* __restrict__ Xt,
                                                const float* __restrict__ bias,
                                                bf16* __restrict__ qt, bf16* __restrict__ kt,
                                                bf16* __restrict__ vt) {
    const int t = threadIdx.x, wave = t >> 6, lane = t & 63;
    const int quad = lane >> 4, l15 = lane & 15;
    const int b   = blockIdx.z;
    const int m0w = blockIdx.y * 128 + (wave >> 1) * 64;
    const int n0w = blockIdx.x * 128 + (wave & 1) * 64;
    const bf16* Ab = Wb + (size_t)(m0w + l15) * 512 + quad * 8;
    const bf16* Bb = Xt + ((size_t)b * NSP + n0w + l15) * 512 + quad * 8;

    f32x4 acc[4][4];
#pragma unroll
    for (int i = 0; i < 4; i++)
#pragma unroll
        for (int j = 0; j < 4; j++) acc[i][j] = (f32x4){0.f, 0.f, 0.f, 0.f};

#pragma unroll 2
    for (int k0 = 0; k0 < 512; k0 += 32) {
        short8 af[4], bfr[4];
#pragma unroll
        for (int mf = 0; mf < 4; mf++) af[mf]  = *(const short8*)(Ab + (size_t)mf * 16 * 512 + k0);
#pragma unroll
        for (int nf = 0; nf < 4; nf++) bfr[nf] = *(const short8*)(Bb + (size_t)nf * 16 * 512 + k0);
#pragma unroll
        for (int mf = 0; mf < 4; mf++)
#pragma unroll
            for (int nf = 0; nf < 4; nf++)
                acc[mf][nf] = __builtin_amdgcn_mfma_f32_16x16x32_bf16(af[mf], bfr[nf], acc[mf][nf], 0, 0, 0);
    }

    const int sec = m0w >> 9, h = (m0w >> 6) & 7, bh = b * NHEAD + h;
    const float sm = (sec == 0) ? SMSCALE : 1.0f;
    float bi[4][4];
#pragma unroll
    for (int mf = 0; mf < 4; mf++)
#pragma unroll
        for (int r = 0; r < 4; r++) bi[mf][r] = bias[m0w + mf * 16 + quad * 4 + r];
#pragma unroll
    for (int mf = 0; mf < 4; mf++)
#pragma unroll
        for (int nf = 0; nf < 4; nf++)
#pragma unroll
            for (int r = 0; r < 4; r++) {
                const float v = (acc[mf][nf][r] + bi[mf][r]) * sm;
                const int n = n0w + nf * 16 + l15;
                const int d = mf * 16 + quad * 4 + r;
                if (sec == 0)      qt[((size_t)bh * NSP + n) * HDIM + d] = tobf(v);
                else if (sec == 1) kt[((size_t)bh * NSP + n) * HDIM + d] = tobf(v);
                else               vt[((size_t)bh * HDIM + d) * NSP + n] = tobf(v);
            }
}

// ---------------- bf16 MFMA GEMM: proj + bias + residual, fp32 out ----------------
__global__ __launch_bounds__(256) void gemm_proj(const bf16* __restrict__ Wb,
                                                 const bf16* __restrict__ Xt,
                                                 const float* __restrict__ bias,
                                                 const float* __restrict__ resid,
                                                 float* __restrict__ out) {
    const int t = threadIdx.x, wave = t >> 6, lane = t & 63;
    const int quad = lane >> 4, l15 = lane & 15;
    const int b   = blockIdx.z;
    const int m0w = blockIdx.y * 128 + (wave >> 1) * 64;
    const int n0w = blockIdx.x * 128 + (wave & 1) * 64;
    const bf16* Ab = Wb + (size_t)(m0w + l15) * 512 + quad * 8;
    const bf16* Bb = Xt + ((size_t)b * NSP + n0w + l15) * 512 + quad * 8;

    f32x4 acc[4][4];
#pragma unroll
    for (int i = 0; i < 4; i++)
#pragma unroll
        for (int j = 0; j < 4; j++) acc[i][j] = (f32x4){0.f, 0.f, 0.f, 0.f};

#pragma unroll 2
    for (int k0 = 0; k0 < 512; k0 += 32) {
        short8 af[4], bfr[4];
#pragma unroll
        for (int mf = 0; mf < 4; mf++) af[mf]  = *(const short8*)(Ab + (size_t)mf * 16 * 512 + k0);
#pragma unroll
        for (int nf = 0; nf < 4; nf++) bfr[nf] = *(const short8*)(Bb + (size_t)nf * 16 * 512 + k0);
#pragma unroll
        for (int mf = 0; mf < 4; mf++)
#pragma unroll
            for (int nf = 0; nf < 4; nf++)
                acc[mf][nf] = __builtin_amdgcn_mfma_f32_16x16x32_bf16(af[mf], bfr[nf], acc[mf][nf], 0, 0, 0);
    }

    float bi[4][4];
#pragma unroll
    for (int mf = 0; mf < 4; mf++)
#pragma unroll
        for (int r = 0; r < 4; r++) bi[mf][r] = bias[m0w + mf * 16 + quad * 4 + r];
#pragma unroll
    for (int mf = 0; mf < 4; mf++)
#pragma unroll
        for (int nf = 0; nf < 4; nf++)
#pragma unroll
            for (int r = 0; r < 4; r++) {
                const int m = m0w + mf * 16 + quad * 4 + r;
                const int n = n0w + nf * 16 + l15;
                const size_t idx = ((size_t)b * CCH + m) * NSP + n;
                out[idx] = acc[mf][nf][r] + bi[mf][r] + resid[idx];
            }
}

// ---------------- MFMA flash attention v2: S^T formulation, no barriers ----------------
// Wave-private everything; 32 queries/wave. Q pre-scaled by 0.125*log2(e) -> exp2f.
__global__ __launch_bounds__(256, 2) void attn2(const bf16* __restrict__ qt,
                                                const bf16* __restrict__ kt,
                                                const bf16* __restrict__ vt,
                                                bf16* __restrict__ att_t) {
    __shared__ __align__(16) bf16 Pl[4][2][16][72];  // [wave][qs][q][key+pad]
    const int t = threadIdx.x, wave = t >> 6, lane = t & 63;
    const int quad = lane >> 4, l15 = lane & 15;
    const int bh = blockIdx.z * NHEAD + blockIdx.y;
    const int qb = blockIdx.x * 128 + wave * 32;

    const bf16* Qb = qt + (size_t)bh * NSP * HDIM;
    const bf16* Kb = kt + (size_t)bh * NSP * HDIM;
    const bf16* Vb = vt + (size_t)bh * HDIM * NSP;

    // Q as B-operand: B[k=dim][n=q], per lane n=l15, k contiguous
    short8 qf[2][2];
#pragma unroll
    for (int qs = 0; qs < 2; qs++)
#pragma unroll
        for (int c = 0; c < 2; c++)
            qf[qs][c] = *(const short8*)(Qb + (size_t)(qb + qs * 16 + l15) * HDIM + c * 32 + quad * 8);

    f32x4 o[2][4];
    float mrow[2] = {-1e30f, -1e30f}, lrow[2] = {0.f, 0.f};
#pragma unroll
    for (int qs = 0; qs < 2; qs++)
#pragma unroll
        for (int ds = 0; ds < 4; ds++) o[qs][ds] = (f32x4){0.f, 0.f, 0.f, 0.f};

#pragma unroll 2
    for (int mt = 0; mt < 64; mt++) {
        const int mb = mt * 64;
        // K as A-operand: A[m=key][k=dim]
        short8 kf[4][2];
#pragma unroll
        for (int ms = 0; ms < 4; ms++)
#pragma unroll
            for (int c = 0; c < 2; c++)
                kf[ms][c] = *(const short8*)(Kb + (size_t)(mb + ms * 16 + l15) * HDIM + c * 32 + quad * 8);

        // S^T[key][q]: row=quad*4+r=key, col=l15=q
        f32x4 s[2][4];
#pragma unroll
        for (int qs = 0; qs < 2; qs++)
#pragma unroll
            for (int ms = 0; ms < 4; ms++) {
                f32x4 a = (f32x4){0.f, 0.f, 0.f, 0.f};
                a = __builtin_amdgcn_mfma_f32_16x16x32_bf16(kf[ms][0], qf[qs][0], a, 0, 0, 0);
                a = __builtin_amdgcn_mfma_f32_16x16x32_bf16(kf[ms][1], qf[qs][1], a, 0, 0, 0);
                s[qs][ms] = a;
            }

        // online softmax: full query column in-lane (16 vals) + 2 cross-quad shuffles
        float alpha[2];
#pragma unroll
        for (int qs = 0; qs < 2; qs++) {
            float mx = s[qs][0][0];
#pragma unroll
            for (int ms = 0; ms < 4; ms++)
#pragma unroll
                for (int r = 0; r < 4; r++) mx = fmaxf(mx, s[qs][ms][r]);
            mx = fmaxf(mx, __shfl_xor(mx, 16, 64));
            mx = fmaxf(mx, __shfl_xor(mx, 32, 64));
            const float nm = fmaxf(mrow[qs], mx);
            const float al = exp2f(mrow[qs] - nm);
            mrow[qs] = nm;
            float rs = 0.f;
#pragma unroll
            for (int ms = 0; ms < 4; ms++) {
#pragma unroll
                for (int r = 0; r < 4; r++) {
                    const float p = exp2f(s[qs][ms][r] - nm);
                    s[qs][ms][r] = p;
                    rs += p;
                }
            }
            rs += __shfl_xor(rs, 16, 64);
            rs += __shfl_xor(rs, 32, 64);
            lrow[qs] = lrow[qs] * al + rs;
            alpha[qs] = al;
            // pack P[q][key]: 4 consecutive keys per lane -> b64
#pragma unroll
            for (int ms = 0; ms < 4; ms++) {
                alignas(8) bf16 pbuf[4];
#pragma unroll
                for (int r = 0; r < 4; r++) pbuf[r] = tobf(s[qs][ms][r]);
                *(unsigned long long*)&Pl[wave][qs][l15][ms * 16 + quad * 4] =
                    *(unsigned long long*)pbuf;
            }
        }

        // P as A-operand: A[m=q][k=key]
        short8 pf[2][2];
#pragma unroll
        for (int qs = 0; qs < 2; qs++)
#pragma unroll
            for (int c = 0; c < 2; c++)
                pf[qs][c] = *(const short8*)&Pl[wave][qs][l15][c * 32 + quad * 8];

        // V as B-operand: B[k=key][n=d]
        short8 vf[4][2];
#pragma unroll
        for (int ds = 0; ds < 4; ds++)
#pragma unroll
            for (int c = 0; c < 2; c++)
                vf[ds][c] = *(const short8*)(Vb + (size_t)(ds * 16 + l15) * NSP + mb + c * 32 + quad * 8);

        float alr[2][4];
#pragma unroll
        for (int qs = 0; qs < 2; qs++)
#pragma unroll
            for (int r = 0; r < 4; r++) alr[qs][r] = __shfl(alpha[qs], quad * 4 + r, 64);

#pragma unroll
        for (int qs = 0; qs < 2; qs++)
#pragma unroll
            for (int ds = 0; ds < 4; ds++) {
                f32x4 a = o[qs][ds];
#pragma unroll
                for (int r = 0; r < 4; r++) a[r] *= alr[qs][r];
                a = __builtin_amdgcn_mfma_f32_16x16x32_bf16(pf[qs][0], vf[ds][0], a, 0, 0, 0);
                a = __builtin_amdgcn_mfma_f32_16x16x32_bf16(pf[qs][1], vf[ds][1], a, 0, 0, 0);
                o[qs][ds] = a;
            }
    }

    // epilogue: att_t[b][n=q][c=h*64+d] bf16
#pragma unroll
    for (int qs = 0; qs < 2; qs++) {
        float linv[4];
#pragma unroll
        for (int r = 0; r < 4; r++) linv[r] = 1.0f / __shfl(lrow[qs], quad * 4 + r, 64);
#pragma unroll
        for (int ds = 0; ds < 4; ds++)
#pragma unroll
            for (int r = 0; r < 4; r++) {
                const int q = qb + qs * 16 + quad * 4 + r;
                att_t[((size_t)blockIdx.z * NSP + q) * CCH + blockIdx.y * HDIM + ds * 16 + l15] =
                    tobf(o[qs][ds][r] * linv[r]);
            }
    }
}

extern "C" void kernel_launch(void* const* d_in, const int* in_sizes, int n_in,
                              void* d_out, int out_size, void* d_ws, size_t ws_size,
                              hipStream_t stream) {
    const float* x    = (const float*)d_in[0];
    const float* nw   = (const float*)d_in[1];
    const float* nb   = (const float*)d_in[2];
    const float* qkvw = (const float*)d_in[3];
    const float* qkvb = (const float*)d_in[4];
    const float* pw   = (const float*)d_in[5];
    const float* pb   = (const float*)d_in[6];
    float* out = (float*)d_out;
    char* ws   = (char*)d_ws;

    float* stats = (float*)ws;                            // 512 B
    bf16* wq  = (bf16*)(ws + (size_t)1  * 1024 * 1024);   // 1.5 MB
    bf16* wp  = (bf16*)(ws + (size_t)3  * 1024 * 1024);   // 0.5 MB
    bf16* hnt = (bf16*)(ws + (size_t)4  * 1024 * 1024);   // 8 MB, reused as att_t
    bf16* qtb = (bf16*)(ws + (size_t)12 * 1024 * 1024);   // 8 MB
    bf16* ktb = (bf16*)(ws + (size_t)20 * 1024 * 1024);   // 8 MB
    bf16* vtb = (bf16*)(ws + (size_t)28 * 1024 * 1024);   // 8 MB
    bf16* att = hnt;

    hipLaunchKernelGGL(wcast, dim3(1024), dim3(256), 0, stream, qkvw, pw, wq, wp);
    hipLaunchKernelGGL(gn_stats, dim3(BATCH * NGRP), dim3(256), 0, stream, x, stats);
    hipLaunchKernelGGL(gn_apply_t, dim3(NSP / 64, CCH / 64, BATCH), dim3(256), 0, stream,
                       x, stats, nw, nb, hnt);
    hipLaunchKernelGGL(gemm_qkv, dim3(NSP / 128, 1536 / 128, BATCH), dim3(256), 0, stream,
                       wq, hnt, qkvb, qtb, ktb, vtb);
    hipLaunchKernelGGL(attn2, dim3(NSP / 128, NHEAD, BATCH), dim3(256), 0, stream,
                       qtb, ktb, vtb, att);
    hipLaunchKernelGGL(gemm_proj, dim3(NSP / 128, CCH / 128, BATCH), dim3(256), 0, stream,
                       wp, att, pb, x, out);
}